// Round 16
// baseline (102.944 us; speedup 1.0000x reference)
//
#include <hip/hip_runtime.h>
#include <hip/hip_bf16.h>

#define B_   2
#define S_   2048
#define H_   16
#define G_   4
#define DH_  64
#define D_   1024
#define DKV_ 256
#define SCALE_ 0.125f
#define LDQK_ 1280   // fused [Q | K] projection row length

using short8  = __attribute__((ext_vector_type(8))) short;
using floatx4 = __attribute__((ext_vector_type(4))) float;
typedef unsigned short ushort_t;

__device__ __forceinline__ ushort_t f2bf(float f) {
    union { float f; unsigned u; } v; v.f = f;
    unsigned r = v.u + 0x7fffu + ((v.u >> 16) & 1u);
    return (ushort_t)(r >> 16);
}
__device__ __forceinline__ float bf2f(ushort_t u) {
    union { unsigned u; float f; } v; v.u = ((unsigned)u) << 16;
    return v.f;
}
__device__ __forceinline__ unsigned cvt_pk_bf16(float lo, float hi) {
    unsigned r;
    asm("v_cvt_pk_bf16_f32 %0, %1, %2" : "=v"(r) : "v"(lo), "v"(hi));
    return r;
}

__device__ __forceinline__ void gload16(const ushort_t* g, ushort_t* l) {
    __builtin_amdgcn_global_load_lds(
        (const __attribute__((address_space(1))) void*)g,
        (__attribute__((address_space(3))) void*)l, 16, 0, 0);
}

// ---------------- fused pack: [X | Wq | Wk | Wv | Wo] -> contiguous bf16 ----------------
__global__ void pack_all(const float* __restrict__ X,  const float* __restrict__ Wq,
                         const float* __restrict__ Wk, const float* __restrict__ Wv,
                         const float* __restrict__ Wo, ushort_t* __restrict__ dst) {
    const int X4  = B_ * S_ * D_ / 4;   // 2097152
    const int QW4 = D_ * D_ / 4;        // 262144
    const int KW4 = DKV_ * D_ / 4;      // 65536
    int i = blockIdx.x * blockDim.x + threadIdx.x;
    const float* src; int off;
    if (i < X4)                        { src = X;  off = i; }
    else if (i < X4 + QW4)             { src = Wq; off = i - X4; }
    else if (i < X4 + QW4 + KW4)       { src = Wk; off = i - X4 - QW4; }
    else if (i < X4 + QW4 + 2 * KW4)   { src = Wv; off = i - X4 - QW4 - KW4; }
    else                               { src = Wo; off = i - X4 - QW4 - 2 * KW4; }
    float4 v = reinterpret_cast<const float4*>(src)[off];
    ushort4 o;
    o.x = f2bf(v.x); o.y = f2bf(v.y); o.z = f2bf(v.z); o.w = f2bf(v.w);
    reinterpret_cast<ushort4*>(dst)[i] = o;
}

// ---------------- unified staged GEMM, 128x64 tile, double-buffered ----------------
// MODE 0 (grid.x=768): bx<640 -> QK proj (bf16 + fused RoPE, ldc=1280);
//                      bx>=640 -> Vt proj (bf16, ldc=2048, per-batch).
// MODE 1 (grid 32x16): out = combine(Y0,Y1,L0,L1) @ Wob^T (f32 out).
//   A staged global->reg with on-the-fly (Y0+Y1)*inv combine + ds_write
//   (source col pre-swizzled, LDS layout identical to gload_lds path).
template<int MODE>
__global__ __launch_bounds__(256)
void gemm_all(const ushort_t* __restrict__ Xb,  const ushort_t* __restrict__ Wqkb,
              const ushort_t* __restrict__ Wvb, const ushort_t* __restrict__ Wob,
              ushort_t* __restrict__ QKb, ushort_t* __restrict__ Vtb,
              const ushort_t* __restrict__ Y0g, const ushort_t* __restrict__ Y1g,
              const float* __restrict__ Lg0, const float* __restrict__ Lg1,
              float* __restrict__ Cout,
              const float* __restrict__ rope, float qscale)
{
    __shared__ __align__(16) ushort_t Asm[2][128 * 64];
    __shared__ __align__(16) ushort_t Bsm[2][64 * 64];

    const ushort_t *Aorig = nullptr, *Borig;
    ushort_t* Cb = nullptr; float* Cf = nullptr;
    int m0, n0, ldc, epi;
    if (MODE == 1) {
        m0 = blockIdx.x * 128; n0 = blockIdx.y * 64;
        Borig = Wob; Cf = Cout; ldc = D_; epi = 1;
    } else {
        const int bx = blockIdx.x;
        if (bx < 640) {
            m0 = (bx / 20) * 128; n0 = (bx % 20) * 64;
            Aorig = Xb; Borig = Wqkb; Cb = QKb; ldc = LDQK_; epi = 2;
        } else {
            const int idx = bx - 640, b = idx >> 6, rem = idx & 63;
            m0 = (rem >> 5) * 128; n0 = (rem & 31) * 64;
            Aorig = Wvb; Borig = Xb + (long)b * S_ * D_;
            Cb = Vtb + (long)b * DKV_ * S_; ldc = S_; epi = 0;
        }
    }

    const int tid = threadIdx.x, l = tid & 63, w = tid >> 6;
    const int wr = (w >> 1) * 64, wc = (w & 1) * 32;
    const int lr = l & 15, lkb = l >> 4;

    const int srow = w * 8 + (l >> 3);
    const int scol = ((l & 7) ^ ((l >> 3) & 7)) * 8;
    const ushort_t* Ast = (MODE == 0) ? Aorig + (long)(m0 + srow) * D_ + scol : nullptr;
    const ushort_t* Bst = Borig + (long)(n0 + srow) * D_ + scol;

    floatx4 acc[4][2] = {};
    const int xr = (lr & 7) << 4;   // read-side XOR (bytes)

    auto do_mfma = [&](int cur) {
#pragma unroll
        for (int ks = 0; ks < 2; ++ks) {
            short8 a[4], bb2[2];
#pragma unroll
            for (int ii = 0; ii < 4; ++ii) {
                const int row = wr + ii * 16 + lr;
                a[ii] = *(const short8*)&Asm[cur][(row * 128 + ((ks * 64 + lkb * 16) ^ xr)) >> 1];
            }
#pragma unroll
            for (int j = 0; j < 2; ++j) {
                const int row = wc + j * 16 + lr;
                bb2[j] = *(const short8*)&Bsm[cur][(row * 128 + ((ks * 64 + lkb * 16) ^ xr)) >> 1];
            }
            __builtin_amdgcn_s_setprio(1);
#pragma unroll
            for (int ii = 0; ii < 4; ++ii)
#pragma unroll
                for (int j = 0; j < 2; ++j)
                    acc[ii][j] = __builtin_amdgcn_mfma_f32_16x16x32_bf16(a[ii], bb2[j], acc[ii][j], 0, 0, 0);
            __builtin_amdgcn_s_setprio(0);
        }
    };

    if (MODE == 0) {
#define GSTAGE(buf, kt)                                                    \
    {                                                                      \
        _Pragma("unroll")                                                  \
        for (int rr = 0; rr < 4; ++rr)                                     \
            gload16(Ast + (long)rr * 32 * D_ + (kt), &Asm[buf][w * 512 + rr * 2048]); \
        _Pragma("unroll")                                                  \
        for (int c = 0; c < 2; ++c)                                        \
            gload16(Bst + (long)c * 32 * D_ + (kt), &Bsm[buf][w * 512 + c * 2048]);   \
    }
        GSTAGE(0, 0);
        for (int i = 0; i < 16; ++i) {
            const int cur = i & 1;
            if (i < 15) {
                GSTAGE(cur ^ 1, (i + 1) * 64);
                asm volatile("s_waitcnt vmcnt(6)" ::: "memory");
            } else {
                asm volatile("s_waitcnt vmcnt(0)" ::: "memory");
            }
            __builtin_amdgcn_s_barrier();
            do_mfma(cur);
            __builtin_amdgcn_s_barrier();
        }
#undef GSTAGE
    } else {
        short8 ya[4], yb[4]; float la[4];
#define ALOAD(i2)                                                          \
    {                                                                      \
        _Pragma("unroll")                                                  \
        for (int rr = 0; rr < 4; ++rr) {                                   \
            const int arow = m0 + rr * 32 + srow;                          \
            const long asrc = (long)arow * D_ + (i2) * 64 + scol;          \
            ya[rr] = *(const short8*)&Y0g[asrc];                           \
            yb[rr] = *(const short8*)&Y1g[asrc];                           \
            la[rr] = Lg0[arow * H_ + (i2)] + Lg1[arow * H_ + (i2)];        \
        }                                                                  \
    }
#define AWRITE(buf)                                                        \
    {                                                                      \
        _Pragma("unroll")                                                  \
        for (int rr = 0; rr < 4; ++rr) {                                   \
            const float inv = 1.f / la[rr];                                \
            union { unsigned u[4]; short8 s; } pk;                         \
            _Pragma("unroll")                                              \
            for (int j = 0; j < 4; ++j) {                                  \
                const float a0 = (bf2f((ushort_t)ya[rr][2*j])   + bf2f((ushort_t)yb[rr][2*j]))   * inv; \
                const float a1 = (bf2f((ushort_t)ya[rr][2*j+1]) + bf2f((ushort_t)yb[rr][2*j+1])) * inv; \
                pk.u[j] = cvt_pk_bf16(a0, a1);                             \
            }                                                              \
            *(short8*)&Asm[buf][w * 512 + rr * 2048 + l * 8] = pk.s;       \
        }                                                                  \
    }
#define BSTG(buf, i2)                                                      \
    {                                                                      \
        _Pragma("unroll")                                                  \
        for (int c = 0; c < 2; ++c)                                        \
            gload16(Bst + (long)c * 32 * D_ + (i2) * 64, &Bsm[buf][w * 512 + c * 2048]); \
    }
        ALOAD(0); BSTG(0, 0);
        asm volatile("s_waitcnt vmcnt(0)" ::: "memory");
        AWRITE(0);
        asm volatile("s_waitcnt lgkmcnt(0)" ::: "memory");
        __builtin_amdgcn_s_barrier();
        for (int i = 0; i < 16; ++i) {
            const int cur = i & 1;
            if (i < 15) { ALOAD(i + 1); BSTG(cur ^ 1, i + 1); }
            do_mfma(cur);
            if (i < 15) {
                asm volatile("s_waitcnt vmcnt(0)" ::: "memory");
                AWRITE(cur ^ 1);
                asm volatile("s_waitcnt lgkmcnt(0)" ::: "memory");
            }
            __builtin_amdgcn_s_barrier();
        }
#undef ALOAD
#undef AWRITE
#undef BSTG
    }

    const int rrow = lkb * 4;
#pragma unroll
    for (int i = 0; i < 4; ++i) {
#pragma unroll
        for (int j = 0; j < 2; ++j) {
#pragma unroll
            for (int r = 0; r < 4; ++r) {
                const int row = m0 + wr + i * 16 + rrow + r;
                const int col = n0 + wc + j * 16 + lr;
                if (epi == 1) {
                    Cf[(long)row * ldc + col] = acc[i][j][r];
                } else if (epi == 0) {
                    Cb[(long)row * ldc + col] = f2bf(acc[i][j][r]);
                } else {
                    const float v  = acc[i][j][r];
                    const float pv = __shfl_xor(v, 1);   // partner column
                    const int   s  = row & (S_ - 1);
                    const int   d  = col & (DH_ - 1);
                    const float cc = rope[s * DH_ + d];
                    const float sn = rope[S_ * DH_ + s * DH_ + d];
                    float res = (lr & 1) ? (v * cc + pv * sn) : (v * cc - pv * sn);
                    res *= (col < D_) ? qscale : 1.0f;
                    Cb[(long)row * ldc + col] = f2bf(res);
                }
            }
        }
    }
}

// ---------------- flash attention v15: 2 tiles/barrier, 4 rotating buffers ----------------
// 8 waves, QBLK=128, kv-split x2 (seg0 = upper half of qt=15-bx, seg1 = lower
// half of qt=bx; exactly 17 64-kv units/block). 4x 64x64 K/V buffers (64 KB);
// each iteration stages tiles i+2,i+3 (clamped dup at tail keeps 4 loads/iter),
// waits vmcnt(4) (new loads stay in flight across barrier), computes 2 tiles
// between barriers. Fixed-max softmax, kv-permuted K rows, ones-MFMA row-sum.
__global__ __launch_bounds__(512)
void attn_kernel(const ushort_t* __restrict__ QK, const ushort_t* __restrict__ Vt,
                 ushort_t* __restrict__ Y0, ushort_t* __restrict__ Y1,
                 float* __restrict__ L0, float* __restrict__ L1)
{
    __shared__ __align__(16) ushort_t Kt [4][64 * 64];
    __shared__ __align__(16) ushort_t Vts[4][64 * 64];

    const int tid = threadIdx.x;
    const int l   = tid & 63;
    const int w   = tid >> 6;            // 8 waves
    const int lr  = l & 15, lkb = l >> 4, lk = lkb * 8;
    const int bx = blockIdx.x, h = blockIdx.y, b = blockIdx.z;
    const int g   = h >> 2;

    const int sr  = l >> 3;
    const int sce = ((l & 7) ^ sr) * 8;
    const ushort_t* Ksrc = QK + (long)b * S_ * LDQK_ + D_ + g * DH_ + sce;
    const ushort_t* Vsrc = Vt + (long)(b * G_ + g) * DH_ * S_ + sce;

    const int rl = w * 8 + sr;
    const int kr = (rl & 0x23) | ((rl & 0x0C) << 1) | ((rl & 0x10) >> 2);  // kv-permuted K row

    short8 vones;
#pragma unroll
    for (int j = 0; j < 8; ++j) vones[j] = (short)0x3F80;   // bf16 1.0

#define STG(bi, tt)                                                       \
    {                                                                     \
        gload16(Ksrc + (long)((tt) * 64 + kr) * LDQK_, &Kt[bi][w * 512]); \
        gload16(Vsrc + (long)rl * S_ + (tt) * 64,      &Vts[bi][w * 512]);\
    }

    for (int seg = 0; seg < 2; ++seg) {
        const int qt = seg == 0 ? (S_ / 128 - 1 - bx) : bx;      // q-tile of 128 rows
        const int t0 = seg == 0 ? qt + 1 : 0;                    // kv 64-units
        const int n  = qt + 1;
        const int tmax = t0 + n - 1;
        const int qrow0 = qt * 128 + w * 16;

        const ushort_t* Qp = QK + ((long)b * S_ + qrow0 + lr) * LDQK_ + h * DH_ + lk;
        const short8 bq0 = *(const short8*)(Qp);
        const short8 bq1 = *(const short8*)(Qp + 32);

        floatx4 o[4] = {};
        floatx4 osum = {};

        auto compute_tile = [&](int cur, int t) {
            // ---- QK^T (A = K rows permuted, B = Q rows) ----
            floatx4 sacc[4] = {};
            __builtin_amdgcn_s_setprio(1);
#pragma unroll
            for (int cf = 0; cf < 4; ++cf) {
                const int row = cf * 16 + lr;
                const int xr  = (row & 7) << 4;
                const short8 ak0 = *(const short8*)&Kt[cur][(row * 128 + ((lkb * 16) ^ xr)) >> 1];
                const short8 ak1 = *(const short8*)&Kt[cur][(row * 128 + ((64 + lkb * 16) ^ xr)) >> 1];
                sacc[cf] = __builtin_amdgcn_mfma_f32_16x16x32_bf16(ak0, bq0, sacc[cf], 0, 0, 0);
                sacc[cf] = __builtin_amdgcn_mfma_f32_16x16x32_bf16(ak1, bq1, sacc[cf], 0, 0, 0);
            }
            __builtin_amdgcn_s_setprio(0);

            // sacc[cf][r] = score at kv = t*64 + 32*(cf>>1) + 8*lkb + 4*(cf&1) + r
            if (t >= 2 * qt) {   // diagonal region (incl. fully-masked sub-tiles)
                const int qg = qrow0 + lr;
#pragma unroll
                for (int cf = 0; cf < 4; ++cf) {
                    const int kvb0 = t * 64 + 32 * (cf >> 1) + 8 * lkb + 4 * (cf & 1);
#pragma unroll
                    for (int r = 0; r < 4; ++r)
                        if (kvb0 + r > qg) sacc[cf][r] = -3e38f;
                }
            }

            // ---- softmax numerator in place: sacc = 2^sacc ----
#pragma unroll
            for (int cf = 0; cf < 4; ++cf)
#pragma unroll
                for (int r = 0; r < 4; ++r)
                    sacc[cf][r] = exp2f(sacc[cf][r]);

            // ---- PV + row-sum via ones-MFMA (A-frag packed from sacc) ----
#pragma unroll
            for (int ks = 0; ks < 2; ++ks) {
                union { unsigned u[4]; short8 s; } pa;
#pragma unroll
                for (int j = 0; j < 4; ++j) {
                    const int cf = 2 * ks + (j >> 1);
                    const int e  = (j & 1) * 2;
                    pa.u[j] = cvt_pk_bf16(sacc[cf][e], sacc[cf][e + 1]);
                }
                __builtin_amdgcn_s_setprio(1);
#pragma unroll
                for (int df = 0; df < 4; ++df) {
                    const int vrow = df * 16 + lr;
                    const int xr   = (vrow & 7) << 4;
                    const short8 bv = *(const short8*)&Vts[cur][(vrow * 128 + ((ks * 64 + lkb * 16) ^ xr)) >> 1];
                    o[df] = __builtin_amdgcn_mfma_f32_16x16x32_bf16(pa.s, bv, o[df], 0, 0, 0);
                }
                osum = __builtin_amdgcn_mfma_f32_16x16x32_bf16(pa.s, vones, osum, 0, 0, 0);
                __builtin_amdgcn_s_setprio(0);
            }
        };

        STG(0, t0);
        STG(1, (t0 + 1 <= tmax) ? t0 + 1 : tmax);

        for (int i = 0; i < n; i += 2) {
            const int tn2 = (t0 + i + 2 <= tmax) ? t0 + i + 2 : tmax;
            const int tn3 = (t0 + i + 3 <= tmax) ? t0 + i + 3 : tmax;
            STG((i + 2) & 3, tn2);
            STG((i + 3) & 3, tn3);
            asm volatile("s_waitcnt vmcnt(4)" ::: "memory");
            __builtin_amdgcn_s_barrier();
            compute_tile(i & 3, t0 + i);
            if (i + 1 < n) compute_tile((i + 1) & 3, t0 + i + 1);
            __builtin_amdgcn_s_barrier();
        }
        asm volatile("s_waitcnt vmcnt(0)" ::: "memory");   // drain tail dup loads

        // ---- raw partial epilogue ----
        ushort_t* Yp = seg == 0 ? Y1 : Y0;
        float*    Lp = seg == 0 ? L1 : L0;
#pragma unroll
        for (int r = 0; r < 4; ++r) {
            const int row = qrow0 + lkb * 4 + r;
#pragma unroll
            for (int df = 0; df < 4; ++df)
                Yp[((long)b * S_ + row) * D_ + h * DH_ + df * 16 + lr] = f2bf(o[df][r]);
            if (lr == 0)
                Lp[((long)b * S_ + row) * H_ + h] = osum[r];
        }
        __builtin_amdgcn_s_barrier();   // safe LDS reuse across segments
    }
#undef STG
}

extern "C" void kernel_launch(void* const* d_in, const int* in_sizes, int n_in,
                              void* d_out, int out_size, void* d_ws, size_t ws_size,
                              hipStream_t stream) {
    const float* X    = (const float*)d_in[0];
    const float* Wq   = (const float*)d_in[1];
    const float* Wk   = (const float*)d_in[2];
    const float* Wv   = (const float*)d_in[3];
    const float* Wo   = (const float*)d_in[4];
    const float* rope = (const float*)d_in[5];
    float* out = (float*)d_out;

    char* ws = (char*)d_ws;
    size_t o = 0;
    ushort_t* Xb   = (ushort_t*)(ws + o); o += (size_t)B_ * S_ * D_ * 2;       // reused as Y0
    ushort_t* Wqkb = (ushort_t*)(ws + o); o += (size_t)LDQK_ * D_ * 2;          // [Wq|Wk]
    ushort_t* Wvb  = (ushort_t*)(ws + o); o += (size_t)DKV_ * D_ * 2;
    ushort_t* Wob  = (ushort_t*)(ws + o); o += (size_t)D_ * D_ * 2;
    ushort_t* QKb  = (ushort_t*)(ws + o); o += (size_t)B_ * S_ * LDQK_ * 2;
    ushort_t* Vtb  = (ushort_t*)(ws + o); o += (size_t)B_ * G_ * DH_ * S_ * 2;
    ushort_t* Y1b  = (ushort_t*)(ws + o); o += (size_t)B_ * S_ * D_ * 2;
    float*    L0   = (float*)(ws + o);    o += (size_t)B_ * S_ * H_ * 4;
    float*    L1   = (float*)(ws + o);    o += (size_t)B_ * S_ * H_ * 4;
    ushort_t* Y0   = Xb;   // X dead after projections

    {
        // Xb, Wqkb, Wvb, Wob contiguous: one fused pack
        int n4 = (B_ * S_ * D_ + 2 * D_ * D_ + 2 * DKV_ * D_) / 4;   // 2752512
        pack_all<<<(n4 + 255) / 256, 256, 0, stream>>>(X, Wq, Wk, Wv, Wo, Xb);
    }

    const float SC2 = SCALE_ * 1.44269504f;
    // fused projections: [Q|K] (with RoPE) + Vt, 768 blocks (3/CU)
    gemm_all<0><<<dim3(768, 1, 1), 256, 0, stream>>>(
        Xb, Wqkb, Wvb, Wob, QKb, Vtb, nullptr, nullptr, nullptr, nullptr,
        nullptr, rope, SC2);

    // 8-wave attention: 16 x H x B = 512 blocks x 512 threads
    attn_kernel<<<dim3(S_ / 128, H_, B_), 512, 0, stream>>>(QKb, Vtb, Y0, Y1b, L0, L1);

    // out = combine(Y0,Y1)/(L0+L1) @ Wo^T (fp32), combine fused into A-staging
    gemm_all<1><<<dim3(32, 16, 1), 256, 0, stream>>>(
        Xb, Wqkb, Wvb, Wob, QKb, Vtb, Y0, Y1b, L0, L1, out, nullptr, 0.f);
}

// Round 17
// 96.318 us; speedup vs baseline: 1.0688x; 1.0688x over previous
//
#include <hip/hip_runtime.h>
#include <hip/hip_bf16.h>

#define B_   2
#define S_   2048
#define H_   16
#define G_   4
#define DH_  64
#define D_   1024
#define DKV_ 256
#define SCALE_ 0.125f
#define LDQK_ 1280   // fused [Q | K] projection row length

using short8  = __attribute__((ext_vector_type(8))) short;
using floatx4 = __attribute__((ext_vector_type(4))) float;
typedef unsigned short ushort_t;

__device__ __forceinline__ ushort_t f2bf(float f) {
    union { float f; unsigned u; } v; v.f = f;
    unsigned r = v.u + 0x7fffu + ((v.u >> 16) & 1u);
    return (ushort_t)(r >> 16);
}
__device__ __forceinline__ float bf2f(ushort_t u) {
    union { unsigned u; float f; } v; v.u = ((unsigned)u) << 16;
    return v.f;
}
__device__ __forceinline__ unsigned cvt_pk_bf16(float lo, float hi) {
    unsigned r;
    asm("v_cvt_pk_bf16_f32 %0, %1, %2" : "=v"(r) : "v"(lo), "v"(hi));
    return r;
}

__device__ __forceinline__ void gload16(const ushort_t* g, ushort_t* l) {
    __builtin_amdgcn_global_load_lds(
        (const __attribute__((address_space(1))) void*)g,
        (__attribute__((address_space(3))) void*)l, 16, 0, 0);
}

// ---------------- fused pack: [X | Wq | Wk | Wv | Wo] -> contiguous bf16 ----------------
__global__ void pack_all(const float* __restrict__ X,  const float* __restrict__ Wq,
                         const float* __restrict__ Wk, const float* __restrict__ Wv,
                         const float* __restrict__ Wo, ushort_t* __restrict__ dst) {
    const int X4  = B_ * S_ * D_ / 4;   // 2097152
    const int QW4 = D_ * D_ / 4;        // 262144
    const int KW4 = DKV_ * D_ / 4;      // 65536
    int i = blockIdx.x * blockDim.x + threadIdx.x;
    const float* src; int off;
    if (i < X4)                        { src = X;  off = i; }
    else if (i < X4 + QW4)             { src = Wq; off = i - X4; }
    else if (i < X4 + QW4 + KW4)       { src = Wk; off = i - X4 - QW4; }
    else if (i < X4 + QW4 + 2 * KW4)   { src = Wv; off = i - X4 - QW4 - KW4; }
    else                               { src = Wo; off = i - X4 - QW4 - 2 * KW4; }
    float4 v = reinterpret_cast<const float4*>(src)[off];
    ushort4 o;
    o.x = f2bf(v.x); o.y = f2bf(v.y); o.z = f2bf(v.z); o.w = f2bf(v.w);
    reinterpret_cast<ushort4*>(dst)[i] = o;
}

// ---------------- unified staged GEMM, 128x64 tile, double-buffered ----------------
// MODE 0 (grid.x=768): bx<640 -> QK proj (bf16 + fused RoPE, ldc=1280);
//                      bx>=640 -> Vt proj (bf16, ldc=2048, per-batch).
// MODE 1 (grid 32x16): out = Yb @ Wob^T (f32 out, ldc=1024).
// 4 waves (2M x 2N): wave tile 64x32 = 4x2 fragments. LDS 48 KB -> 3 blocks/CU.
template<int MODE>
__global__ __launch_bounds__(256)
void gemm_all(const ushort_t* __restrict__ Xb,  const ushort_t* __restrict__ Wqkb,
              const ushort_t* __restrict__ Wvb, const ushort_t* __restrict__ Wob,
              ushort_t* __restrict__ QKb, ushort_t* __restrict__ Vtb,
              const ushort_t* __restrict__ Yb, float* __restrict__ Cout,
              const float* __restrict__ rope, float qscale)
{
    __shared__ __align__(16) ushort_t Asm[2][128 * 64];
    __shared__ __align__(16) ushort_t Bsm[2][64 * 64];

    const ushort_t *Aorig, *Borig;
    ushort_t* Cb = nullptr; float* Cf = nullptr;
    int m0, n0, ldc, epi;
    if (MODE == 1) {
        m0 = blockIdx.x * 128; n0 = blockIdx.y * 64;
        Aorig = Yb; Borig = Wob; Cf = Cout; ldc = D_; epi = 1;
    } else {
        const int bx = blockIdx.x;
        if (bx < 640) {
            m0 = (bx / 20) * 128; n0 = (bx % 20) * 64;
            Aorig = Xb; Borig = Wqkb; Cb = QKb; ldc = LDQK_; epi = 2;
        } else {
            const int idx = bx - 640, b = idx >> 6, rem = idx & 63;
            m0 = (rem >> 5) * 128; n0 = (rem & 31) * 64;
            Aorig = Wvb; Borig = Xb + (long)b * S_ * D_;
            Cb = Vtb + (long)b * DKV_ * S_; ldc = S_; epi = 0;
        }
    }

    const int tid = threadIdx.x, l = tid & 63, w = tid >> 6;
    const int wr = (w >> 1) * 64, wc = (w & 1) * 32;
    const int lr = l & 15, lkb = l >> 4;

    const int srow = w * 8 + (l >> 3);
    const int scol = ((l & 7) ^ ((l >> 3) & 7)) * 8;
    const ushort_t* Ast = Aorig + (long)(m0 + srow) * D_ + scol;
    const ushort_t* Bst = Borig + (long)(n0 + srow) * D_ + scol;

#define GSTAGE(buf, kt)                                                    \
    {                                                                      \
        _Pragma("unroll")                                                  \
        for (int rr = 0; rr < 4; ++rr)                                     \
            gload16(Ast + (long)rr * 32 * D_ + (kt), &Asm[buf][w * 512 + rr * 2048]); \
        _Pragma("unroll")                                                  \
        for (int c = 0; c < 2; ++c)                                        \
            gload16(Bst + (long)c * 32 * D_ + (kt), &Bsm[buf][w * 512 + c * 2048]);   \
    }

    floatx4 acc[4][2] = {};
    const int xr = (lr & 7) << 4;   // read-side XOR (bytes)
    GSTAGE(0, 0);
    for (int i = 0; i < 16; ++i) {
        const int cur = i & 1;
        if (i < 15) {
            GSTAGE(cur ^ 1, (i + 1) * 64);
            asm volatile("s_waitcnt vmcnt(6)" ::: "memory");
        } else {
            asm volatile("s_waitcnt vmcnt(0)" ::: "memory");
        }
        __builtin_amdgcn_s_barrier();

#pragma unroll
        for (int ks = 0; ks < 2; ++ks) {
            short8 a[4], bb[2];
#pragma unroll
            for (int ii = 0; ii < 4; ++ii) {
                const int row = wr + ii * 16 + lr;
                a[ii] = *(const short8*)&Asm[cur][(row * 128 + ((ks * 64 + lkb * 16) ^ xr)) >> 1];
            }
#pragma unroll
            for (int j = 0; j < 2; ++j) {
                const int row = wc + j * 16 + lr;
                bb[j] = *(const short8*)&Bsm[cur][(row * 128 + ((ks * 64 + lkb * 16) ^ xr)) >> 1];
            }
            __builtin_amdgcn_s_setprio(1);
#pragma unroll
            for (int ii = 0; ii < 4; ++ii)
#pragma unroll
                for (int j = 0; j < 2; ++j)
                    acc[ii][j] = __builtin_amdgcn_mfma_f32_16x16x32_bf16(a[ii], bb[j], acc[ii][j], 0, 0, 0);
            __builtin_amdgcn_s_setprio(0);
        }
        __builtin_amdgcn_s_barrier();
    }
#undef GSTAGE

    const int rrow = lkb * 4;
#pragma unroll
    for (int i = 0; i < 4; ++i) {
#pragma unroll
        for (int j = 0; j < 2; ++j) {
#pragma unroll
            for (int r = 0; r < 4; ++r) {
                const int row = m0 + wr + i * 16 + rrow + r;
                const int col = n0 + wc + j * 16 + lr;
                if (epi == 1) {
                    Cf[(long)row * ldc + col] = acc[i][j][r];
                } else if (epi == 0) {
                    Cb[(long)row * ldc + col] = f2bf(acc[i][j][r]);
                } else {
                    const float v  = acc[i][j][r];
                    const float pv = __shfl_xor(v, 1);   // partner column
                    const int   s  = row & (S_ - 1);
                    const int   d  = col & (DH_ - 1);
                    const float cc = rope[s * DH_ + d];
                    const float sn = rope[S_ * DH_ + s * DH_ + d];
                    float res = (lr & 1) ? (v * cc + pv * sn) : (v * cc - pv * sn);
                    res *= (col < D_) ? qscale : 1.0f;
                    Cb[(long)row * ldc + col] = f2bf(res);
                }
            }
        }
    }
}

// ---------------- flash attention v15: 2 tiles/barrier, 4 rotating buffers ----------------
// 8 waves, QBLK=128, kv-split x2 (seg0 = upper half of qt=15-bx, seg1 = lower
// half of qt=bx; exactly 17 64-kv units/block). 4x 64x64 K/V buffers (64 KB);
// each iteration stages tiles i+2,i+3 (clamped dup at tail keeps 4 loads/iter),
// waits vmcnt(4) (new loads stay in flight across barrier), computes 2 tiles
// between barriers. Fixed-max softmax, kv-permuted K rows, ones-MFMA row-sum.
__global__ __launch_bounds__(512)
void attn_kernel(const ushort_t* __restrict__ QK, const ushort_t* __restrict__ Vt,
                 ushort_t* __restrict__ Y0, ushort_t* __restrict__ Y1,
                 float* __restrict__ L0, float* __restrict__ L1)
{
    __shared__ __align__(16) ushort_t Kt [4][64 * 64];
    __shared__ __align__(16) ushort_t Vts[4][64 * 64];

    const int tid = threadIdx.x;
    const int l   = tid & 63;
    const int w   = tid >> 6;            // 8 waves
    const int lr  = l & 15, lkb = l >> 4, lk = lkb * 8;
    const int bx = blockIdx.x, h = blockIdx.y, b = blockIdx.z;
    const int g   = h >> 2;

    const int sr  = l >> 3;
    const int sce = ((l & 7) ^ sr) * 8;
    const ushort_t* Ksrc = QK + (long)b * S_ * LDQK_ + D_ + g * DH_ + sce;
    const ushort_t* Vsrc = Vt + (long)(b * G_ + g) * DH_ * S_ + sce;

    const int rl = w * 8 + sr;
    const int kr = (rl & 0x23) | ((rl & 0x0C) << 1) | ((rl & 0x10) >> 2);  // kv-permuted K row

    short8 vones;
#pragma unroll
    for (int j = 0; j < 8; ++j) vones[j] = (short)0x3F80;   // bf16 1.0

#define STG(bi, tt)                                                       \
    {                                                                     \
        gload16(Ksrc + (long)((tt) * 64 + kr) * LDQK_, &Kt[bi][w * 512]); \
        gload16(Vsrc + (long)rl * S_ + (tt) * 64,      &Vts[bi][w * 512]);\
    }

    for (int seg = 0; seg < 2; ++seg) {
        const int qt = seg == 0 ? (S_ / 128 - 1 - bx) : bx;      // q-tile of 128 rows
        const int t0 = seg == 0 ? qt + 1 : 0;                    // kv 64-units
        const int n  = qt + 1;
        const int tmax = t0 + n - 1;
        const int qrow0 = qt * 128 + w * 16;

        const ushort_t* Qp = QK + ((long)b * S_ + qrow0 + lr) * LDQK_ + h * DH_ + lk;
        const short8 bq0 = *(const short8*)(Qp);
        const short8 bq1 = *(const short8*)(Qp + 32);

        floatx4 o[4] = {};
        floatx4 osum = {};

        auto compute_tile = [&](int cur, int t) {
            // ---- QK^T (A = K rows permuted, B = Q rows) ----
            floatx4 sacc[4] = {};
            __builtin_amdgcn_s_setprio(1);
#pragma unroll
            for (int cf = 0; cf < 4; ++cf) {
                const int row = cf * 16 + lr;
                const int xr  = (row & 7) << 4;
                const short8 ak0 = *(const short8*)&Kt[cur][(row * 128 + ((lkb * 16) ^ xr)) >> 1];
                const short8 ak1 = *(const short8*)&Kt[cur][(row * 128 + ((64 + lkb * 16) ^ xr)) >> 1];
                sacc[cf] = __builtin_amdgcn_mfma_f32_16x16x32_bf16(ak0, bq0, sacc[cf], 0, 0, 0);
                sacc[cf] = __builtin_amdgcn_mfma_f32_16x16x32_bf16(ak1, bq1, sacc[cf], 0, 0, 0);
            }
            __builtin_amdgcn_s_setprio(0);

            // sacc[cf][r] = score at kv = t*64 + 32*(cf>>1) + 8*lkb + 4*(cf&1) + r
            if (t >= 2 * qt) {   // diagonal region (incl. fully-masked sub-tiles)
                const int qg = qrow0 + lr;
#pragma unroll
                for (int cf = 0; cf < 4; ++cf) {
                    const int kvb0 = t * 64 + 32 * (cf >> 1) + 8 * lkb + 4 * (cf & 1);
#pragma unroll
                    for (int r = 0; r < 4; ++r)
                        if (kvb0 + r > qg) sacc[cf][r] = -3e38f;
                }
            }

            // ---- softmax numerator in place: sacc = 2^sacc ----
#pragma unroll
            for (int cf = 0; cf < 4; ++cf)
#pragma unroll
                for (int r = 0; r < 4; ++r)
                    sacc[cf][r] = exp2f(sacc[cf][r]);

            // ---- PV + row-sum via ones-MFMA (A-frag packed from sacc) ----
#pragma unroll
            for (int ks = 0; ks < 2; ++ks) {
                union { unsigned u[4]; short8 s; } pa;
#pragma unroll
                for (int j = 0; j < 4; ++j) {
                    const int cf = 2 * ks + (j >> 1);
                    const int e  = (j & 1) * 2;
                    pa.u[j] = cvt_pk_bf16(sacc[cf][e], sacc[cf][e + 1]);
                }
                __builtin_amdgcn_s_setprio(1);
#pragma unroll
                for (int df = 0; df < 4; ++df) {
                    const int vrow = df * 16 + lr;
                    const int xr   = (vrow & 7) << 4;
                    const short8 bv = *(const short8*)&Vts[cur][(vrow * 128 + ((ks * 64 + lkb * 16) ^ xr)) >> 1];
                    o[df] = __builtin_amdgcn_mfma_f32_16x16x32_bf16(pa.s, bv, o[df], 0, 0, 0);
                }
                osum = __builtin_amdgcn_mfma_f32_16x16x32_bf16(pa.s, vones, osum, 0, 0, 0);
                __builtin_amdgcn_s_setprio(0);
            }
        };

        STG(0, t0);
        STG(1, (t0 + 1 <= tmax) ? t0 + 1 : tmax);

        for (int i = 0; i < n; i += 2) {
            const int tn2 = (t0 + i + 2 <= tmax) ? t0 + i + 2 : tmax;
            const int tn3 = (t0 + i + 3 <= tmax) ? t0 + i + 3 : tmax;
            STG((i + 2) & 3, tn2);
            STG((i + 3) & 3, tn3);
            asm volatile("s_waitcnt vmcnt(4)" ::: "memory");
            __builtin_amdgcn_s_barrier();
            compute_tile(i & 3, t0 + i);
            if (i + 1 < n) compute_tile((i + 1) & 3, t0 + i + 1);
            __builtin_amdgcn_s_barrier();
        }
        asm volatile("s_waitcnt vmcnt(0)" ::: "memory");   // drain tail dup loads

        // ---- raw partial epilogue ----
        ushort_t* Yp = seg == 0 ? Y1 : Y0;
        float*    Lp = seg == 0 ? L1 : L0;
#pragma unroll
        for (int r = 0; r < 4; ++r) {
            const int row = qrow0 + lkb * 4 + r;
#pragma unroll
            for (int df = 0; df < 4; ++df)
                Yp[((long)b * S_ + row) * D_ + h * DH_ + df * 16 + lr] = f2bf(o[df][r]);
            if (lr == 0)
                Lp[((long)b * S_ + row) * H_ + h] = osum[r];
        }
        __builtin_amdgcn_s_barrier();   // safe LDS reuse across segments
    }
#undef STG
}

// ---------------- combine: Y = (Y0 + Y1) / (L0 + L1), in-place into Y0 ----------------
__global__ void combine_kernel(ushort_t* __restrict__ Y0, const ushort_t* __restrict__ Y1,
                               const float* __restrict__ L0, const float* __restrict__ L1) {
    const int i  = blockIdx.x * blockDim.x + threadIdx.x;   // over B*S*D/8 chunks
    const int row = i >> 7;          // D/8 = 128 chunks per row
    const int h   = (i & 127) >> 3;  // 8 chunks per head
    const float inv = 1.f / (L0[row * H_ + h] + L1[row * H_ + h]);
    const short8 y0 = ((const short8*)Y0)[i];
    const short8 y1 = ((const short8*)Y1)[i];
    union { unsigned u[4]; short8 s; } o;
#pragma unroll
    for (int j = 0; j < 4; ++j) {
        const float a = (bf2f((ushort_t)y0[2 * j])     + bf2f((ushort_t)y1[2 * j]))     * inv;
        const float c = (bf2f((ushort_t)y0[2 * j + 1]) + bf2f((ushort_t)y1[2 * j + 1])) * inv;
        o.u[j] = cvt_pk_bf16(a, c);
    }
    ((short8*)Y0)[i] = o.s;
}

extern "C" void kernel_launch(void* const* d_in, const int* in_sizes, int n_in,
                              void* d_out, int out_size, void* d_ws, size_t ws_size,
                              hipStream_t stream) {
    const float* X    = (const float*)d_in[0];
    const float* Wq   = (const float*)d_in[1];
    const float* Wk   = (const float*)d_in[2];
    const float* Wv   = (const float*)d_in[3];
    const float* Wo   = (const float*)d_in[4];
    const float* rope = (const float*)d_in[5];
    float* out = (float*)d_out;

    char* ws = (char*)d_ws;
    size_t o = 0;
    ushort_t* Xb   = (ushort_t*)(ws + o); o += (size_t)B_ * S_ * D_ * 2;       // reused as Y0
    ushort_t* Wqkb = (ushort_t*)(ws + o); o += (size_t)LDQK_ * D_ * 2;          // [Wq|Wk]
    ushort_t* Wvb  = (ushort_t*)(ws + o); o += (size_t)DKV_ * D_ * 2;
    ushort_t* Wob  = (ushort_t*)(ws + o); o += (size_t)D_ * D_ * 2;
    ushort_t* QKb  = (ushort_t*)(ws + o); o += (size_t)B_ * S_ * LDQK_ * 2;
    ushort_t* Vtb  = (ushort_t*)(ws + o); o += (size_t)B_ * G_ * DH_ * S_ * 2;
    ushort_t* Y1b  = (ushort_t*)(ws + o); o += (size_t)B_ * S_ * D_ * 2;
    float*    L0   = (float*)(ws + o);    o += (size_t)B_ * S_ * H_ * 4;
    float*    L1   = (float*)(ws + o);    o += (size_t)B_ * S_ * H_ * 4;
    ushort_t* Y0   = Xb;   // X dead after projections

    {
        // Xb, Wqkb, Wvb, Wob contiguous: one fused pack
        int n4 = (B_ * S_ * D_ + 2 * D_ * D_ + 2 * DKV_ * D_) / 4;   // 2752512
        pack_all<<<(n4 + 255) / 256, 256, 0, stream>>>(X, Wq, Wk, Wv, Wo, Xb);
    }

    const float SC2 = SCALE_ * 1.44269504f;
    // fused projections: [Q|K] (with RoPE) + Vt, 768 blocks (3/CU)
    gemm_all<0><<<dim3(768, 1, 1), 256, 0, stream>>>(
        Xb, Wqkb, Wvb, Wob, QKb, Vtb, nullptr, nullptr, rope, SC2);

    // 8-wave attention: 16 x H x B = 512 blocks x 512 threads
    attn_kernel<<<dim3(S_ / 128, H_, B_), 512, 0, stream>>>(QKb, Vtb, Y0, Y1b, L0, L1);

    // combine partials -> Y0 (bf16, normalized)
    {
        int nthr = B_ * S_ * D_ / 8;   // 524288
        combine_kernel<<<nthr / 256, 256, 0, stream>>>(Y0, Y1b, L0, L1);
    }

    // out = Y @ Wo^T (fp32), 512 blocks
    gemm_all<1><<<dim3(32, 16, 1), 256, 0, stream>>>(
        Xb, Wqkb, Wvb, Wob, QKb, Vtb, Y0, out, nullptr, 0.f);
}

// Round 18
// 93.322 us; speedup vs baseline: 1.1031x; 1.0321x over previous
//
#include <hip/hip_runtime.h>
#include <hip/hip_bf16.h>

#define B_   2
#define S_   2048
#define H_   16
#define G_   4
#define DH_  64
#define D_   1024
#define DKV_ 256
#define SCALE_ 0.125f
#define LDQK_ 1280   // fused [Q | K] projection row length

using short8  = __attribute__((ext_vector_type(8))) short;
using floatx4 = __attribute__((ext_vector_type(4))) float;
typedef unsigned short ushort_t;

__device__ __forceinline__ ushort_t f2bf(float f) {
    union { float f; unsigned u; } v; v.f = f;
    unsigned r = v.u + 0x7fffu + ((v.u >> 16) & 1u);
    return (ushort_t)(r >> 16);
}
__device__ __forceinline__ float bf2f(ushort_t u) {
    union { unsigned u; float f; } v; v.u = ((unsigned)u) << 16;
    return v.f;
}
__device__ __forceinline__ unsigned cvt_pk_bf16(float lo, float hi) {
    unsigned r;
    asm("v_cvt_pk_bf16_f32 %0, %1, %2" : "=v"(r) : "v"(lo), "v"(hi));
    return r;
}

__device__ __forceinline__ void gload16(const ushort_t* g, ushort_t* l) {
    __builtin_amdgcn_global_load_lds(
        (const __attribute__((address_space(1))) void*)g,
        (__attribute__((address_space(3))) void*)l, 16, 0, 0);
}

// ---------------- fused pack: [X | Wq | Wk | Wv | Wo] -> contiguous bf16 ----------------
__global__ void pack_all(const float* __restrict__ X,  const float* __restrict__ Wq,
                         const float* __restrict__ Wk, const float* __restrict__ Wv,
                         const float* __restrict__ Wo, ushort_t* __restrict__ dst) {
    const int X4  = B_ * S_ * D_ / 4;   // 2097152
    const int QW4 = D_ * D_ / 4;        // 262144
    const int KW4 = DKV_ * D_ / 4;      // 65536
    int i = blockIdx.x * blockDim.x + threadIdx.x;
    const float* src; int off;
    if (i < X4)                        { src = X;  off = i; }
    else if (i < X4 + QW4)             { src = Wq; off = i - X4; }
    else if (i < X4 + QW4 + KW4)       { src = Wk; off = i - X4 - QW4; }
    else if (i < X4 + QW4 + 2 * KW4)   { src = Wv; off = i - X4 - QW4 - KW4; }
    else                               { src = Wo; off = i - X4 - QW4 - 2 * KW4; }
    float4 v = reinterpret_cast<const float4*>(src)[off];
    ushort4 o;
    o.x = f2bf(v.x); o.y = f2bf(v.y); o.z = f2bf(v.z); o.w = f2bf(v.w);
    reinterpret_cast<ushort4*>(dst)[i] = o;
}

// ---------------- unified staged GEMM, 128x64 tile, double-buffered ----------------
// MODE 0 (grid.x=768): f<640 -> QK proj (bf16 + fused RoPE, ldc=1280), XCD-clustered
//                      by m-panel (xcd=f&7 -> mt=xcd+8*(j%4), nt=j/4);
//                      f>=640 -> Vt proj (bf16, ldc=2048, per-batch).
// MODE 1 (grid 32x16): out = Yb @ Wob^T (f32, ldc=1024), XCD-clustered by Y-panel.
template<int MODE>
__global__ __launch_bounds__(256)
void gemm_all(const ushort_t* __restrict__ Xb,  const ushort_t* __restrict__ Wqkb,
              const ushort_t* __restrict__ Wvb, const ushort_t* __restrict__ Wob,
              ushort_t* __restrict__ QKb, ushort_t* __restrict__ Vtb,
              const ushort_t* __restrict__ Yb, float* __restrict__ Cout,
              const float* __restrict__ rope, float qscale)
{
    __shared__ __align__(16) ushort_t Asm[2][128 * 64];
    __shared__ __align__(16) ushort_t Bsm[2][64 * 64];

    const ushort_t *Aorig, *Borig;
    ushort_t* Cb = nullptr; float* Cf = nullptr;
    int m0, n0, ldc, epi;
    if (MODE == 1) {
        const int f = blockIdx.x + 32 * blockIdx.y;    // [0,512)
        const int xcd = f & 7, j = f >> 3;             // j in [0,64)
        m0 = (xcd + 8 * (j & 3)) * 128;                // 32 m-tiles, clustered per XCD
        n0 = (j >> 2) * 64;                            // 16 n-tiles
        Aorig = Yb; Borig = Wob; Cf = Cout; ldc = D_; epi = 1;
    } else {
        const int f = blockIdx.x;
        if (f < 640) {
            const int xcd = f & 7, j = f >> 3;         // j in [0,80)
            m0 = (xcd + 8 * (j & 3)) * 128;            // 32 m-tiles, clustered per XCD
            n0 = (j >> 2) * 64;                        // 20 n-tiles
            Aorig = Xb; Borig = Wqkb; Cb = QKb; ldc = LDQK_; epi = 2;
        } else {
            const int idx = f - 640, b = idx >> 6, rem = idx & 63;
            m0 = (rem >> 5) * 128; n0 = (rem & 31) * 64;
            Aorig = Wvb; Borig = Xb + (long)b * S_ * D_;
            Cb = Vtb + (long)b * DKV_ * S_; ldc = S_; epi = 0;
        }
    }

    const int tid = threadIdx.x, l = tid & 63, w = tid >> 6;
    const int wr = (w >> 1) * 64, wc = (w & 1) * 32;
    const int lr = l & 15, lkb = l >> 4;

    const int srow = w * 8 + (l >> 3);
    const int scol = ((l & 7) ^ ((l >> 3) & 7)) * 8;
    const ushort_t* Ast = Aorig + (long)(m0 + srow) * D_ + scol;
    const ushort_t* Bst = Borig + (long)(n0 + srow) * D_ + scol;

#define GSTAGE(buf, kt)                                                    \
    {                                                                      \
        _Pragma("unroll")                                                  \
        for (int rr = 0; rr < 4; ++rr)                                     \
            gload16(Ast + (long)rr * 32 * D_ + (kt), &Asm[buf][w * 512 + rr * 2048]); \
        _Pragma("unroll")                                                  \
        for (int c = 0; c < 2; ++c)                                        \
            gload16(Bst + (long)c * 32 * D_ + (kt), &Bsm[buf][w * 512 + c * 2048]);   \
    }

    floatx4 acc[4][2] = {};
    const int xr = (lr & 7) << 4;   // read-side XOR (bytes)
    GSTAGE(0, 0);
    for (int i = 0; i < 16; ++i) {
        const int cur = i & 1;
        if (i < 15) {
            GSTAGE(cur ^ 1, (i + 1) * 64);
            asm volatile("s_waitcnt vmcnt(6)" ::: "memory");
        } else {
            asm volatile("s_waitcnt vmcnt(0)" ::: "memory");
        }
        __builtin_amdgcn_s_barrier();

#pragma unroll
        for (int ks = 0; ks < 2; ++ks) {
            short8 a[4], bb[2];
#pragma unroll
            for (int ii = 0; ii < 4; ++ii) {
                const int row = wr + ii * 16 + lr;
                a[ii] = *(const short8*)&Asm[cur][(row * 128 + ((ks * 64 + lkb * 16) ^ xr)) >> 1];
            }
#pragma unroll
            for (int j = 0; j < 2; ++j) {
                const int row = wc + j * 16 + lr;
                bb[j] = *(const short8*)&Bsm[cur][(row * 128 + ((ks * 64 + lkb * 16) ^ xr)) >> 1];
            }
            __builtin_amdgcn_s_setprio(1);
#pragma unroll
            for (int ii = 0; ii < 4; ++ii)
#pragma unroll
                for (int j = 0; j < 2; ++j)
                    acc[ii][j] = __builtin_amdgcn_mfma_f32_16x16x32_bf16(a[ii], bb[j], acc[ii][j], 0, 0, 0);
            __builtin_amdgcn_s_setprio(0);
        }
        __builtin_amdgcn_s_barrier();
    }
#undef GSTAGE

    const int rrow = lkb * 4;
#pragma unroll
    for (int i = 0; i < 4; ++i) {
#pragma unroll
        for (int j = 0; j < 2; ++j) {
#pragma unroll
            for (int r = 0; r < 4; ++r) {
                const int row = m0 + wr + i * 16 + rrow + r;
                const int col = n0 + wc + j * 16 + lr;
                if (epi == 1) {
                    Cf[(long)row * ldc + col] = acc[i][j][r];
                } else if (epi == 0) {
                    Cb[(long)row * ldc + col] = f2bf(acc[i][j][r]);
                } else {
                    const float v  = acc[i][j][r];
                    const float pv = __shfl_xor(v, 1);   // partner column
                    const int   s  = row & (S_ - 1);
                    const int   d  = col & (DH_ - 1);
                    const float cc = rope[s * DH_ + d];
                    const float sn = rope[S_ * DH_ + s * DH_ + d];
                    float res = (lr & 1) ? (v * cc + pv * sn) : (v * cc - pv * sn);
                    res *= (col < D_) ? qscale : 1.0f;
                    Cb[(long)row * ldc + col] = f2bf(res);
                }
            }
        }
    }
}

// ---------------- flash attention v16: v15 pipeline + XCD-pinned (b,g) ----------------
// Flat block id remapped so all 64 blocks sharing (b, g) land on ONE XCD
// (f&7 = xcd -> b=xcd>>2, g=xcd&3): per-XCD K/V working set = 512 KB, L2-resident.
// 8 waves, QBLK=128, kv-split x2 (seg0 = upper half of qt=15-bx, seg1 = lower
// half of qt=bx; exactly 17 64-kv units/block). 4x 64x64 K/V buffers (64 KB);
// stage i+2,i+3 per iter (clamped dup at tail), vmcnt(4), compute 2 tiles per
// barrier window. Fixed-max softmax, kv-permuted K rows, ones-MFMA row-sum.
__global__ __launch_bounds__(512)
void attn_kernel(const ushort_t* __restrict__ QK, const ushort_t* __restrict__ Vt,
                 ushort_t* __restrict__ Y0, ushort_t* __restrict__ Y1,
                 float* __restrict__ L0, float* __restrict__ L1)
{
    __shared__ __align__(16) ushort_t Kt [4][64 * 64];
    __shared__ __align__(16) ushort_t Vts[4][64 * 64];

    const int tid = threadIdx.x;
    const int l   = tid & 63;
    const int w   = tid >> 6;            // 8 waves
    const int lr  = l & 15, lkb = l >> 4, lk = lkb * 8;

    // XCD-pinning remap: f = flat dispatch id; xcd = f&7 fixes (b,g)
    const int f   = blockIdx.x + 16 * (blockIdx.y + 16 * blockIdx.z);
    const int xcd = f & 7, j = f >> 3;   // j in [0,64)
    const int b   = xcd >> 2;
    const int g   = xcd & 3;
    const int h   = g * 4 + (j & 3);
    const int bx  = j >> 2;              // [0,16)

    const int sr  = l >> 3;
    const int sce = ((l & 7) ^ sr) * 8;
    const ushort_t* Ksrc = QK + (long)b * S_ * LDQK_ + D_ + g * DH_ + sce;
    const ushort_t* Vsrc = Vt + (long)(b * G_ + g) * DH_ * S_ + sce;

    const int rl = w * 8 + sr;
    const int kr = (rl & 0x23) | ((rl & 0x0C) << 1) | ((rl & 0x10) >> 2);  // kv-permuted K row

    short8 vones;
#pragma unroll
    for (int jj = 0; jj < 8; ++jj) vones[jj] = (short)0x3F80;   // bf16 1.0

#define STG(bi, tt)                                                       \
    {                                                                     \
        gload16(Ksrc + (long)((tt) * 64 + kr) * LDQK_, &Kt[bi][w * 512]); \
        gload16(Vsrc + (long)rl * S_ + (tt) * 64,      &Vts[bi][w * 512]);\
    }

    for (int seg = 0; seg < 2; ++seg) {
        const int qt = seg == 0 ? (S_ / 128 - 1 - bx) : bx;      // q-tile of 128 rows
        const int t0 = seg == 0 ? qt + 1 : 0;                    // kv 64-units
        const int n  = qt + 1;
        const int tmax = t0 + n - 1;
        const int qrow0 = qt * 128 + w * 16;

        const ushort_t* Qp = QK + ((long)b * S_ + qrow0 + lr) * LDQK_ + h * DH_ + lk;
        const short8 bq0 = *(const short8*)(Qp);
        const short8 bq1 = *(const short8*)(Qp + 32);

        floatx4 o[4] = {};
        floatx4 osum = {};

        auto compute_tile = [&](int cur, int t) {
            // ---- QK^T (A = K rows permuted, B = Q rows) ----
            floatx4 sacc[4] = {};
            __builtin_amdgcn_s_setprio(1);
#pragma unroll
            for (int cf = 0; cf < 4; ++cf) {
                const int row = cf * 16 + lr;
                const int xr  = (row & 7) << 4;
                const short8 ak0 = *(const short8*)&Kt[cur][(row * 128 + ((lkb * 16) ^ xr)) >> 1];
                const short8 ak1 = *(const short8*)&Kt[cur][(row * 128 + ((64 + lkb * 16) ^ xr)) >> 1];
                sacc[cf] = __builtin_amdgcn_mfma_f32_16x16x32_bf16(ak0, bq0, sacc[cf], 0, 0, 0);
                sacc[cf] = __builtin_amdgcn_mfma_f32_16x16x32_bf16(ak1, bq1, sacc[cf], 0, 0, 0);
            }
            __builtin_amdgcn_s_setprio(0);

            // sacc[cf][r] = score at kv = t*64 + 32*(cf>>1) + 8*lkb + 4*(cf&1) + r
            if (t >= 2 * qt) {   // diagonal region (incl. fully-masked sub-tiles)
                const int qg = qrow0 + lr;
#pragma unroll
                for (int cf = 0; cf < 4; ++cf) {
                    const int kvb0 = t * 64 + 32 * (cf >> 1) + 8 * lkb + 4 * (cf & 1);
#pragma unroll
                    for (int r = 0; r < 4; ++r)
                        if (kvb0 + r > qg) sacc[cf][r] = -3e38f;
                }
            }

            // ---- softmax numerator in place: sacc = 2^sacc ----
#pragma unroll
            for (int cf = 0; cf < 4; ++cf)
#pragma unroll
                for (int r = 0; r < 4; ++r)
                    sacc[cf][r] = exp2f(sacc[cf][r]);

            // ---- PV + row-sum via ones-MFMA (A-frag packed from sacc) ----
#pragma unroll
            for (int ks = 0; ks < 2; ++ks) {
                union { unsigned u[4]; short8 s; } pa;
#pragma unroll
                for (int jj = 0; jj < 4; ++jj) {
                    const int cf = 2 * ks + (jj >> 1);
                    const int e  = (jj & 1) * 2;
                    pa.u[jj] = cvt_pk_bf16(sacc[cf][e], sacc[cf][e + 1]);
                }
                __builtin_amdgcn_s_setprio(1);
#pragma unroll
                for (int df = 0; df < 4; ++df) {
                    const int vrow = df * 16 + lr;
                    const int xr   = (vrow & 7) << 4;
                    const short8 bv = *(const short8*)&Vts[cur][(vrow * 128 + ((ks * 64 + lkb * 16) ^ xr)) >> 1];
                    o[df] = __builtin_amdgcn_mfma_f32_16x16x32_bf16(pa.s, bv, o[df], 0, 0, 0);
                }
                osum = __builtin_amdgcn_mfma_f32_16x16x32_bf16(pa.s, vones, osum, 0, 0, 0);
                __builtin_amdgcn_s_setprio(0);
            }
        };

        STG(0, t0);
        STG(1, (t0 + 1 <= tmax) ? t0 + 1 : tmax);

        for (int i = 0; i < n; i += 2) {
            const int tn2 = (t0 + i + 2 <= tmax) ? t0 + i + 2 : tmax;
            const int tn3 = (t0 + i + 3 <= tmax) ? t0 + i + 3 : tmax;
            STG((i + 2) & 3, tn2);
            STG((i + 3) & 3, tn3);
            asm volatile("s_waitcnt vmcnt(4)" ::: "memory");
            __builtin_amdgcn_s_barrier();
            compute_tile(i & 3, t0 + i);
            if (i + 1 < n) compute_tile((i + 1) & 3, t0 + i + 1);
            __builtin_amdgcn_s_barrier();
        }
        asm volatile("s_waitcnt vmcnt(0)" ::: "memory");   // drain tail dup loads

        // ---- raw partial epilogue ----
        ushort_t* Yp = seg == 0 ? Y1 : Y0;
        float*    Lp = seg == 0 ? L1 : L0;
#pragma unroll
        for (int r = 0; r < 4; ++r) {
            const int row = qrow0 + lkb * 4 + r;
#pragma unroll
            for (int df = 0; df < 4; ++df)
                Yp[((long)b * S_ + row) * D_ + h * DH_ + df * 16 + lr] = f2bf(o[df][r]);
            if (lr == 0)
                Lp[((long)b * S_ + row) * H_ + h] = osum[r];
        }
        __builtin_amdgcn_s_barrier();   // safe LDS reuse across segments
    }
#undef STG
}

// ---------------- combine: Y = (Y0 + Y1) / (L0 + L1), in-place into Y0 ----------------
__global__ void combine_kernel(ushort_t* __restrict__ Y0, const ushort_t* __restrict__ Y1,
                               const float* __restrict__ L0, const float* __restrict__ L1) {
    const int i  = blockIdx.x * blockDim.x + threadIdx.x;   // over B*S*D/8 chunks
    const int row = i >> 7;          // D/8 = 128 chunks per row
    const int h   = (i & 127) >> 3;  // 8 chunks per head
    const float inv = 1.f / (L0[row * H_ + h] + L1[row * H_ + h]);
    const short8 y0 = ((const short8*)Y0)[i];
    const short8 y1 = ((const short8*)Y1)[i];
    union { unsigned u[4]; short8 s; } o;
#pragma unroll
    for (int j = 0; j < 4; ++j) {
        const float a = (bf2f((ushort_t)y0[2 * j])     + bf2f((ushort_t)y1[2 * j]))     * inv;
        const float c = (bf2f((ushort_t)y0[2 * j + 1]) + bf2f((ushort_t)y1[2 * j + 1])) * inv;
        o.u[j] = cvt_pk_bf16(a, c);
    }
    ((short8*)Y0)[i] = o.s;
}

extern "C" void kernel_launch(void* const* d_in, const int* in_sizes, int n_in,
                              void* d_out, int out_size, void* d_ws, size_t ws_size,
                              hipStream_t stream) {
    const float* X    = (const float*)d_in[0];
    const float* Wq   = (const float*)d_in[1];
    const float* Wk   = (const float*)d_in[2];
    const float* Wv   = (const float*)d_in[3];
    const float* Wo   = (const float*)d_in[4];
    const float* rope = (const float*)d_in[5];
    float* out = (float*)d_out;

    char* ws = (char*)d_ws;
    size_t o = 0;
    ushort_t* Xb   = (ushort_t*)(ws + o); o += (size_t)B_ * S_ * D_ * 2;       // reused as Y0
    ushort_t* Wqkb = (ushort_t*)(ws + o); o += (size_t)LDQK_ * D_ * 2;          // [Wq|Wk]
    ushort_t* Wvb  = (ushort_t*)(ws + o); o += (size_t)DKV_ * D_ * 2;
    ushort_t* Wob  = (ushort_t*)(ws + o); o += (size_t)D_ * D_ * 2;
    ushort_t* QKb  = (ushort_t*)(ws + o); o += (size_t)B_ * S_ * LDQK_ * 2;
    ushort_t* Vtb  = (ushort_t*)(ws + o); o += (size_t)B_ * G_ * DH_ * S_ * 2;
    ushort_t* Y1b  = (ushort_t*)(ws + o); o += (size_t)B_ * S_ * D_ * 2;
    float*    L0   = (float*)(ws + o);    o += (size_t)B_ * S_ * H_ * 4;
    float*    L1   = (float*)(ws + o);    o += (size_t)B_ * S_ * H_ * 4;
    ushort_t* Y0   = Xb;   // X dead after projections

    {
        // Xb, Wqkb, Wvb, Wob contiguous: one fused pack
        int n4 = (B_ * S_ * D_ + 2 * D_ * D_ + 2 * DKV_ * D_) / 4;   // 2752512
        pack_all<<<(n4 + 255) / 256, 256, 0, stream>>>(X, Wq, Wk, Wv, Wo, Xb);
    }

    const float SC2 = SCALE_ * 1.44269504f;
    // fused projections: [Q|K] (with RoPE) + Vt, 768 blocks (3/CU), XCD-clustered
    gemm_all<0><<<dim3(768, 1, 1), 256, 0, stream>>>(
        Xb, Wqkb, Wvb, Wob, QKb, Vtb, nullptr, nullptr, rope, SC2);

    // 8-wave attention: 512 blocks x 512 threads, (b,g) pinned per XCD
    attn_kernel<<<dim3(S_ / 128, H_, B_), 512, 0, stream>>>(QKb, Vtb, Y0, Y1b, L0, L1);

    // combine partials -> Y0 (bf16, normalized)
    {
        int nthr = B_ * S_ * D_ / 8;   // 524288
        combine_kernel<<<nthr / 256, 256, 0, stream>>>(Y0, Y1b, L0, L1);
    }

    // out = Y @ Wo^T (fp32), 512 blocks, XCD-clustered
    gemm_all<1><<<dim3(32, 16, 1), 256, 0, stream>>>(
        Xb, Wqkb, Wvb, Wob, QKb, Vtb, Y0, out, nullptr, 0.f);
}